// Round 16
// baseline (124.359 us; speedup 1.0000x reference)
//
#include <hip/hip_runtime.h>
#include <cstdint>
#include <cstddef>

#define NPTS 8192
#define NUM_CLASSES 5
#define XCOLS 10          // 3 coords + batch + feat + 5 seg
#define EPS2 225.0f
#define MIN_PTS 5
#define NGROUPS 10
#define BIGC 0x3fffffff

#define NLCAP 1536        // max nodes per group (expect ~820)
#define NSLICE 8          // row slices (blocks) per group
#define SCAP 2048         // per-(group,slice) private edge capacity (expect ~680)
#define EACAP 12288       // LDS edge cap in graph phase (expect ~5.4k)
#define KR 3              // row strips per lane (3*64*8 = 1536 = NLCAP)
#define ROUNDS 16
#define DPAD 16           // done[] padding (64 B apart)

// ---- group id of point i from raw x row (strict > = jnp.argmax) ----
__device__ __forceinline__ int group_of(const float* __restrict__ x, int i) {
    const float* r = x + (size_t)i * XCOLS;
    int b = (int)r[3];
    float best = r[5]; int bc = 0;
    #pragma unroll
    for (int c = 1; c < NUM_CLASSES; c++) {
        float v = r[5 + c];
        if (v > best) { best = v; bc = c; }
    }
    return b * NUM_CLASSES + bc;
}

// ---------------- init: zero the per-group arrival counters ------------------
__global__ void k_init(unsigned int* __restrict__ done) {
    int i = threadIdx.x;
    if (i < NGROUPS * DPAD) done[i] = 0u;
}

// ---------------- fused: nodes + pairs + (last block) graph ------------------
// grid = 10 groups x 8 slices; block 1024 thr (16 waves).
__global__ void __launch_bounds__(1024) k_fused(
        const float* __restrict__ x,
        unsigned int* __restrict__ edges,     // (g*8+s)*SCAP private slices
        int* __restrict__ ecnt,               // 80 counts (single writer each)
        int* __restrict__ deg_g,              // 10*NLCAP full degrees
        unsigned int* __restrict__ done,
        float* __restrict__ out) {
    __shared__ unsigned long long masks[NPTS / 64];   // 1 KB
    __shared__ int pref[NPTS / 64];                   // 0.5 KB
    __shared__ float4 pts[NLCAP];                     // 24 KB
    __shared__ int nlist[NLCAP];                      // 6 KB
    __shared__ int srowdeg[NLCAP / NSLICE];           // 768 B
    __shared__ int sdeg[NLCAP];                       // 6 KB -> cid array later
    __shared__ int spar[NLCAP];                       // 6 KB
    __shared__ int sbmin[NLCAP];                      // 6 KB
    __shared__ unsigned int eA[EACAP];                // 48 KB
    __shared__ unsigned long long corebm[NLCAP/64];   // 192 B
    __shared__ unsigned long long repbm[NLCAP/64];    // 192 B
    __shared__ int flags[ROUNDS];
    __shared__ int nnS, lcnt, iswin, eoff[NSLICE + 1];

    const int g = blockIdx.x / NSLICE;
    const int s = blockIdx.x % NSLICE;
    const int tid = threadIdx.x, lane = tid & 63, wv = tid >> 6;

    // ---- Phase A: derive ordered node list for group g (all 16 waves) ----
    if (tid == 0) { lcnt = 0; }
    for (int w = wv; w < NPTS / 64; w += 16) {
        int i = w * 64 + lane;
        unsigned long long bm = __ballot(group_of(x, i) == g);
        if (lane == 0) masks[w] = bm;
    }
    __syncthreads();
    if (wv == 0) {                          // 2-chunk scan of 128 popcounts
        int v0 = __popcll(masks[lane]);
        int incl = v0;
        #pragma unroll
        for (int st = 1; st < 64; st <<= 1) {
            int o = __shfl_up(incl, st);
            if (lane >= st) incl += o;
        }
        pref[lane] = incl - v0;
        int tot0 = __shfl(incl, 63);
        int v1 = __popcll(masks[64 + lane]);
        int incl1 = v1;
        #pragma unroll
        for (int st = 1; st < 64; st <<= 1) {
            int o = __shfl_up(incl1, st);
            if (lane >= st) incl1 += o;
        }
        pref[64 + lane] = tot0 + incl1 - v1;
        if (lane == 63) nnS = (tot0 + incl1 > NLCAP) ? NLCAP : (tot0 + incl1);
    }
    __syncthreads();
    for (int w = wv; w < NPTS / 64; w += 16) {
        int i = w * 64 + lane;
        unsigned long long bm = masks[w];
        if ((bm >> lane) & 1ull) {
            int p = pref[w] + __popcll(bm & ((1ull << lane) - 1ull));
            if (p < NLCAP) nlist[p] = i;
        }
    }
    __syncthreads();
    const int nn = nnS;

    // gather coords (p2 inline); sentinel-pad
    for (int k = tid; k < NLCAP; k += 1024) {
        if (k < nn) {
            const float* r = x + (size_t)nlist[k] * XCOLS;
            float px = r[0], py = r[1], pz = r[2];
            pts[k] = make_float4(px, py, pz, px*px + py*py + pz*pz);
        } else {
            pts[k] = make_float4(0.f, 0.f, 0.f, 3.0e38f);
        }
    }
    for (int m = tid; m < NLCAP / NSLICE; m += 1024) srowdeg[m] = 0;
    __syncthreads();

    // ---- Phase B: pair slice (rows r==s mod 8); wave wq owns chunks c==wq mod 16
    int rrow[KR]; float4 qu[KR]; int rowdeg[KR];
    #pragma unroll
    for (int k = 0; k < KR; k++) {
        rrow[k] = s + 8 * (lane + 64 * k);            // < 1536
        qu[k] = pts[rrow[k]];
        rowdeg[k] = 0;
    }
    const int NC = (nn + 31) >> 5;
    unsigned int* eg = edges + (size_t)(g * NSLICE + s) * SCAP;
    for (int c = wv; c < NC; c += 16) {
        int base = c << 5;
        unsigned int bits[KR];
        #pragma unroll
        for (int k = 0; k < KR; k++) bits[k] = 0u;
        #pragma unroll
        for (int t = 0; t < 32; t++) {
            float4 qv = pts[base + t];                // wave-uniform broadcast
            #pragma unroll
            for (int k = 0; k < KR; k++) {
                if (s + 512 * k < nn) {               // uniform strip guard
                    float d2 = qu[k].w + qv.w - 2.0f * (qu[k].x*qv.x + qu[k].y*qv.y + qu[k].z*qv.z);
                    bits[k] |= (d2 < EPS2) ? (1u << t) : 0u;
                }
            }
        }
        int cnt = 0;
        #pragma unroll
        for (int k = 0; k < KR; k++) {
            if (s + 512 * k < nn) {
                rowdeg[k] += __popc(bits[k]);         // FULL adjacency (incl self)
                int d = rrow[k] - base;               // emission: keep v > u
                if (d >= 31) bits[k] = 0u;
                else if (d >= 0) bits[k] &= ~((2u << d) - 1u);
                cnt += __popc(bits[k]);
            }
        }
        int incl = cnt;
        #pragma unroll
        for (int st = 1; st < 64; st <<= 1) {
            int o = __shfl_up(incl, st);
            if (lane >= st) incl += o;
        }
        int tot = __shfl(incl, 63);
        if (tot > 0) {
            int rbase = 0;
            if (lane == 63) rbase = atomicAdd(&lcnt, tot);   // LDS atomic
            rbase = __shfl(rbase, 63);
            int p = rbase + incl - cnt;
            #pragma unroll
            for (int k = 0; k < KR; k++) {
                if (s + 512 * k < nn) {
                    unsigned int b = bits[k];
                    unsigned int uhi = (unsigned int)rrow[k] << 11;
                    while (b) {
                        int t = __ffs(b) - 1; b &= b - 1;
                        if (p < SCAP) eg[p] = uhi | (unsigned int)(base + t);
                        p++;
                    }
                }
            }
        }
    }
    #pragma unroll
    for (int k = 0; k < KR; k++)
        if (rowdeg[k] > 0) atomicAdd(&srowdeg[lane + 64 * k], rowdeg[k]);
    __syncthreads();
    // unique owner of rows r==s (mod 8): plain stores
    for (int m = tid; m < NLCAP / NSLICE; m += 1024)
        deg_g[g * NLCAP + s + 8 * m] = srowdeg[m];
    if (tid == 0) ecnt[g * NSLICE + s] = (lcnt > SCAP) ? SCAP : lcnt;

    // ---- arrival: release stores, last block proceeds ----
    __syncthreads();
    __threadfence();                                   // device-scope release
    if (tid == 0) {
        unsigned int old = __hip_atomic_fetch_add(&done[g * DPAD], 1u,
                              __ATOMIC_ACQ_REL, __HIP_MEMORY_SCOPE_AGENT);
        iswin = (old == NSLICE - 1) ? 1 : 0;
    }
    __syncthreads();
    if (!iswin) return;
    __threadfence();                                   // acquire side

    // ---- Phase C: graph (winner block only; nlist/nn already in LDS) ----
    const int NN = nn;
    if (tid < ROUNDS) flags[tid] = 0;
    if (tid < NSLICE) eoff[tid + 1] = ecnt[g * NSLICE + tid];
    if (tid == 0) eoff[0] = 0;
    for (int k = tid; k < NLCAP; k += 1024) {
        sdeg[k] = deg_g[g * NLCAP + k];
        spar[k] = k;
        sbmin[k] = BIGC;
    }
    __syncthreads();
    if (tid == 0) {
        #pragma unroll
        for (int t = 0; t < NSLICE; t++) {
            int v2 = eoff[t] + eoff[t + 1];
            eoff[t + 1] = (v2 > EACAP) ? EACAP : v2;
        }
    }
    __syncthreads();
    for (int s2 = 0; s2 < NSLICE; s2++) {
        int o0 = eoff[s2], cnt = eoff[s2 + 1] - o0;
        const unsigned int* src = edges + (size_t)(g * NSLICE + s2) * SCAP;
        for (int k = tid; k < cnt; k += 1024) eA[o0 + k] = src[k];
    }
    __syncthreads();
    const int NA = eoff[NSLICE];

    // core bitmap
    for (int w = wv; w < NLCAP / 64; w += 16) {
        int l = w * 64 + lane;
        bool isc = (l < NN) && (sdeg[l] >= MIN_PTS);
        unsigned long long bm = __ballot(isc);
        if (lane == 0) corebm[w] = bm;
    }
    __syncthreads();
    auto corebit = [&](int l) -> bool { return (corebm[l >> 6] >> (l & 63)) & 1ull; };

    // SV rounds: corebit-gated hook-to-min + double pointer jump
    for (int r = 0; r < ROUNDS; r++) {
        for (int k = tid; k < NA; k += 1024) {
            unsigned int pk = eA[k];
            int u = (int)(pk >> 11), v = (int)(pk & 2047u);
            if (corebit(u) && corebit(v)) {
                int a = spar[u], b2 = spar[v];
                if (a < b2)      { int old = atomicMin(&spar[v], a);  if (old > a)  flags[r] = 1; }
                else if (b2 < a) { int old = atomicMin(&spar[u], b2); if (old > b2) flags[r] = 1; }
            }
        }
        __syncthreads();
        for (int k = tid; k < NN; k += 1024) {
            int p1 = spar[k]; int p2 = spar[p1];
            if (p2 < p1) { p1 = spar[p2]; spar[k] = (p1 < p2) ? p1 : p2; flags[r] = 1; }
        }
        __syncthreads();
        if (!flags[r]) break;
    }

    // reps + rank into sdeg (wave 0 serial over 24 words)
    for (int w = wv; w < NLCAP / 64; w += 16) {
        int l = w * 64 + lane;
        bool isr = (l < NN) && corebit(l) && (spar[l] == l);
        unsigned long long bm = __ballot(isr);
        if (lane == 0) repbm[w] = bm;
    }
    __syncthreads();
    if (wv == 0) {
        int running = 0;
        for (int w = 0; w < NLCAP / 64; w++) {
            unsigned long long bm = repbm[w];
            if ((bm >> lane) & 1ull)
                sdeg[w * 64 + lane] = running + __popcll(bm & ((1ull << lane) - 1ull));
            running += __popcll(bm);
        }
    }
    __syncthreads();
    // ccid -> overwrite spar
    int cc[2];
    #pragma unroll
    for (int t = 0; t < 2; t++) {
        int k = tid + t * 1024;
        cc[t] = (k < NN && corebit(k)) ? sdeg[spar[k]] : BIGC;
    }
    __syncthreads();
    #pragma unroll
    for (int t = 0; t < 2; t++) {
        int k = tid + t * 1024;
        if (k < NN) spar[k] = cc[t];
    }
    __syncthreads();
    // border: min adjacent core cid for the non-core endpoint
    for (int k = tid; k < NA; k += 1024) {
        unsigned int pk = eA[k];
        int u = (int)(pk >> 11), v = (int)(pk & 2047u);
        int cu = spar[u], cv = spar[v];
        if (cu == BIGC) { if (cv != BIGC) atomicMin(&sbmin[u], cv); }
        else if (cv == BIGC) atomicMin(&sbmin[v], cu);
    }
    __syncthreads();
    // final labels + clustered output
    for (int k = tid; k < NN; k += 1024) {
        int i = nlist[k];
        int c = spar[k];
        int lbl = (c != BIGC) ? c : ((sbmin[k] < BIGC) ? sbmin[k] : -1);
        out[i] = (float)lbl;
        const float* r = x + (size_t)i * XCOLS;
        float* o = out + NPTS + (size_t)i * 5;
        bool keep = lbl >= 0;
        #pragma unroll
        for (int c5 = 0; c5 < 5; c5++) o[c5] = keep ? r[c5] : 0.0f;
    }
}

extern "C" void kernel_launch(void* const* d_in, const int* in_sizes, int n_in,
                              void* d_out, int out_size, void* d_ws, size_t ws_size,
                              hipStream_t stream) {
    const float* x = (const float*)d_in[0];
    float* out = (float*)d_out;
    char* ws = (char*)d_ws;

    // workspace layout (~720 KB)
    unsigned int* done  = (unsigned int*)(ws);            // 10*16*4 = 640
    int* ecnt           = (int*)(ws + 1024);              // 80*4 = 320
    int* deg_g          = (int*)(ws + 2048);              // 10*1536*4 = 61440
    unsigned int* edges = (unsigned int*)(ws + 63488);    // 80*2048*4 = 655360

    k_init<<<1, 256, 0, stream>>>(done);
    k_fused<<<NGROUPS * NSLICE, 1024, 0, stream>>>(x, edges, ecnt, deg_g, done, out);
}